// Round 2
// baseline (689.763 us; speedup 1.0000x reference)
//
#include <hip/hip_runtime.h>
#include <hip/hip_bf16.h>
#include <stdint.h>

#define D_EMBED 1024
#define D_HID   4096
#define N_TOK   4096
#define N_EXP   8
#define CAP     4096

typedef __attribute__((ext_vector_type(4))) float f32x4;
typedef __attribute__((ext_vector_type(8))) short bf16x8;

__device__ __forceinline__ unsigned short f2bf(float f) {
    unsigned int u = __builtin_bit_cast(unsigned int, f);
    u += 0x7fffu + ((u >> 16) & 1u);          // round-to-nearest-even
    return (unsigned short)(u >> 16);
}

__device__ __forceinline__ void gload_lds16(const void* g, void* l) {
    __builtin_amdgcn_global_load_lds(
        (const __attribute__((address_space(1))) unsigned int*)g,
        (__attribute__((address_space(3))) unsigned int*)l,
        16, 0, 0);
}

// ---------------- x f32 -> bf16 ----------------
__global__ __launch_bounds__(256) void xcvt_kernel(const float* __restrict__ x,
                                                   unsigned short* __restrict__ xb, int n) {
    int i = (blockIdx.x * 256 + threadIdx.x) * 8;
    if (i >= n) return;
    f32x4 a = *reinterpret_cast<const f32x4*>(x + i);
    f32x4 b = *reinterpret_cast<const f32x4*>(x + i + 4);
    bf16x8 o;
    o[0]=(short)f2bf(a[0]); o[1]=(short)f2bf(a[1]); o[2]=(short)f2bf(a[2]); o[3]=(short)f2bf(a[3]);
    o[4]=(short)f2bf(b[0]); o[5]=(short)f2bf(b[1]); o[6]=(short)f2bf(b[2]); o[7]=(short)f2bf(b[3]);
    *reinterpret_cast<bf16x8*>(xb + i) = o;
}

// ------- pack W [E][R][C] f32 -> tiled bf16 [E][R/8 kslice][C][8 j] -------
// element (e,ks,col,j) = W[e][ks*8 + j][col]
__global__ __launch_bounds__(256) void pack_w(const float* __restrict__ W,
                                              unsigned short* __restrict__ out, int R, int C) {
    int e = blockIdx.z, kb = blockIdx.y, cb = blockIdx.x;
    const float* Wp = W + (size_t)e * R * C + (size_t)(kb * 64) * C + cb * 64;
    unsigned short* op = out + (size_t)e * R * C;
    __shared__ unsigned short lds[64][72];
    int t = threadIdx.x;
    int r = t >> 2;
    int c0 = (t & 3) << 4;
    const float* src = Wp + (size_t)r * C + c0;
#pragma unroll
    for (int i = 0; i < 2; ++i) {
        f32x4 a = *reinterpret_cast<const f32x4*>(src + i * 8);
        f32x4 b = *reinterpret_cast<const f32x4*>(src + i * 8 + 4);
        bf16x8 o;
        o[0]=(short)f2bf(a[0]); o[1]=(short)f2bf(a[1]); o[2]=(short)f2bf(a[2]); o[3]=(short)f2bf(a[3]);
        o[4]=(short)f2bf(b[0]); o[5]=(short)f2bf(b[1]); o[6]=(short)f2bf(b[2]); o[7]=(short)f2bf(b[3]);
        *reinterpret_cast<bf16x8*>(&lds[r][c0 + i * 8]) = o;
    }
    __syncthreads();
#pragma unroll
    for (int i = 0; i < 2; ++i) {
        int cell = i * 256 + t;            // 0..511
        int ksl = cell >> 6, col = cell & 63;
        bf16x8 o;
#pragma unroll
        for (int j = 0; j < 8; ++j) o[j] = (short)lds[ksl * 8 + j][col];
        *reinterpret_cast<bf16x8*>(op + ((size_t)(kb * 8 + ksl) * C + cb * 64 + col) * 8) = o;
    }
}

// ---------------- gating ----------------
__global__ __launch_bounds__(256) void gate_kernel(const float* __restrict__ x,
                                                   const float* __restrict__ Wg,
                                                   int* __restrict__ counts,
                                                   int* __restrict__ toks,
                                                   float* __restrict__ wgts,
                                                   int* __restrict__ slots) {
    int wave = threadIdx.x >> 6;
    int lane = threadIdx.x & 63;
    int tok = blockIdx.x * 4 + wave;
    const float* xp = x + (size_t)tok * D_EMBED;
    float acc[8] = {0, 0, 0, 0, 0, 0, 0, 0};
#pragma unroll
    for (int i = 0; i < 16; ++i) {
        int d = lane + 64 * i;
        float xv = xp[d];
        f32x4 w0 = *reinterpret_cast<const f32x4*>(Wg + (size_t)d * 8);
        f32x4 w1 = *reinterpret_cast<const f32x4*>(Wg + (size_t)d * 8 + 4);
        acc[0] += xv * w0[0]; acc[1] += xv * w0[1]; acc[2] += xv * w0[2]; acc[3] += xv * w0[3];
        acc[4] += xv * w1[0]; acc[5] += xv * w1[1]; acc[6] += xv * w1[2]; acc[7] += xv * w1[3];
    }
#pragma unroll
    for (int e = 0; e < 8; ++e)
        for (int s = 32; s; s >>= 1) acc[e] += __shfl_xor(acc[e], s, 64);
    if (lane == 0) {
        int i0 = 0; float v0 = acc[0];
#pragma unroll
        for (int e = 1; e < 8; ++e) if (acc[e] > v0) { v0 = acc[e]; i0 = e; }
        int i1 = -1; float v1 = -1e30f;
#pragma unroll
        for (int e = 0; e < 8; ++e) if (e != i0 && acc[e] > v1) { v1 = acc[e]; i1 = e; }
        float ex = __expf(v1 - v0);
        float w0 = 1.0f / (1.0f + ex);
        float w1 = 1.0f - w0;
        int p0 = atomicAdd(&counts[i0], 1);
        toks[i0 * CAP + p0] = tok; wgts[i0 * CAP + p0] = w0; slots[i0 * CAP + p0] = 0;
        int p1 = atomicAdd(&counts[i1], 1);
        toks[i1 * CAP + p1] = tok; wgts[i1 * CAP + p1] = w1; slots[i1 * CAP + p1] = 1;
    }
}

__global__ void prefix_kernel(const int* __restrict__ counts, int* __restrict__ offsets) {
    if (threadIdx.x == 0) {
        int s = 0;
        for (int e = 0; e < N_EXP; ++e) { offsets[e] = s; s += counts[e]; }
    }
}

__global__ __launch_bounds__(256) void build_map_kernel(const int* __restrict__ counts,
                                                        const int* __restrict__ offsets,
                                                        const int* __restrict__ toks,
                                                        const int* __restrict__ slots,
                                                        int* __restrict__ tok2row) {
    int i = blockIdx.x * 256 + threadIdx.x;     // e*CAP + pos
    int e = i >> 12, pos = i & (CAP - 1);
    if (pos < counts[e])
        tok2row[toks[i] * 2 + slots[i]] = offsets[e] + pos;
}

// ---------------- GEMM1: h = w * silu(X@W1) * (X@W3), interleaved B ----------------
__global__ __launch_bounds__(256, 4) void gemm1_kernel(
    const unsigned short* __restrict__ xb,
    const unsigned short* __restrict__ wt1,
    const unsigned short* __restrict__ wt3,
    const int* __restrict__ counts, const int* __restrict__ offsets,
    const int* __restrict__ toks, const float* __restrict__ wgts,
    unsigned short* __restrict__ h) {
    // flat rowtile -> (expert, rowbase): balanced grid, no empty 128-row tiles
    int rt = blockIdx.x;
    int e = -1, base = 0, rowbase = 0, cnt = 0;
    for (int ee = 0; ee < N_EXP; ++ee) {
        int c = counts[ee];
        int nt = (c + 127) >> 7;
        if (rt < base + nt) { e = ee; rowbase = (rt - base) << 7; cnt = c; break; }
        base += nt;
    }
    if (e < 0) return;
    int off = offsets[e];
    int colp = blockIdx.y * 128;                // packed col base (2 cols per real col pair)

    __shared__ __align__(16) char lds[2][16384];    // [buf][ A 8K | B 8K ]

    int t = threadIdx.x, lane = t & 63, wave = t >> 6;
    int wr = wave >> 1, wc = wave & 1;
    int q = lane >> 4, p = lane & 15;

    const unsigned short* wt1e = wt1 + (size_t)e * D_EMBED * D_HID;
    const unsigned short* wt3e = wt3 + (size_t)e * D_EMBED * D_HID;

    int r0 = rowbase + lane;      if (r0 >= cnt) r0 = cnt - 1;
    int r1 = rowbase + 64 + lane; if (r1 >= cnt) r1 = cnt - 1;
    const unsigned short* pA0 = xb + (size_t)toks[e * CAP + r0] * D_EMBED;
    const unsigned short* pA1 = xb + (size_t)toks[e * CAP + r1] * D_EMBED;

    // per-lane interleaved B source: packed col pc -> (W1|W3, real col)
    int pc0 = colp + lane, pc1 = colp + 64 + lane;
    int g0 = pc0 >> 4, g1 = pc1 >> 4;
    const unsigned short* pB0 = ((g0 & 1) ? wt3e : wt1e) + (size_t)(((g0 >> 1) << 4) | (pc0 & 15)) * 8;
    const unsigned short* pB1 = ((g1 & 1) ? wt3e : wt1e) + (size_t)(((g1 >> 1) << 4) | (pc1 & 15)) * 8;

    f32x4 acc[4][4] = {};
    int aOff = (q * 128 + wr * 64 + p) * 16;
    int bOff = 8192 + (q * 128 + wc * 64 + p) * 16;

    auto STAGE = [&](int buf, int kt) {
        char* L = lds[buf];
        int ksl = wave;                          // 4 waves cover ksl 0..3
        gload_lds16(pA0 + kt * 32 + ksl * 8, L + ksl * 2048);
        gload_lds16(pA1 + kt * 32 + ksl * 8, L + ksl * 2048 + 1024);
        gload_lds16(pB0 + (size_t)(kt * 4 + ksl) * (D_HID * 8), L + 8192 + ksl * 2048);
        gload_lds16(pB1 + (size_t)(kt * 4 + ksl) * (D_HID * 8), L + 8192 + ksl * 2048 + 1024);
    };
    auto COMPUTE = [&](int buf) {
        char* L = lds[buf];
        bf16x8 af[4];
#pragma unroll
        for (int m = 0; m < 4; ++m)
            af[m] = *reinterpret_cast<const bf16x8*>(L + aOff + m * 256);
#pragma unroll
        for (int n = 0; n < 4; ++n) {
            bf16x8 bn = *reinterpret_cast<const bf16x8*>(L + bOff + n * 256);
#pragma unroll
            for (int m = 0; m < 4; ++m)
                acc[m][n] = __builtin_amdgcn_mfma_f32_16x16x32_bf16(af[m], bn, acc[m][n], 0, 0, 0);
        }
    };

    STAGE(0, 0);
    __syncthreads();
    int cur = 0;
#pragma unroll 1
    for (int kt = 0; kt < 31; ++kt) {           // K=1024 / BK=32
        STAGE(cur ^ 1, kt + 1);                 // prefetch overlaps MFMA below
        COMPUTE(cur);
        __syncthreads();                        // single vmcnt(0)+barrier per tile
        cur ^= 1;
    }
    COMPUTE(cur);

#pragma unroll
    for (int m = 0; m < 4; ++m) {
#pragma unroll
        for (int reg = 0; reg < 4; ++reg) {
            int rl = wr * 64 + m * 16 + q * 4 + reg;
            int grow = rowbase + rl;
            if (grow >= cnt) continue;
            float w = wgts[e * CAP + grow];
            size_t hbase = (size_t)(off + grow) * D_HID + blockIdx.y * 64 + wc * 32;
#pragma unroll
            for (int np = 0; np < 2; ++np) {
                float a1 = acc[m][2 * np][reg];      // even group -> W1
                float a3 = acc[m][2 * np + 1][reg];  // odd group  -> W3
                float hv = (a1 / (1.0f + __expf(-a1))) * a3 * w;
                h[hbase + np * 16 + p] = f2bf(hv);
            }
        }
    }
}

// ---------------- GEMM2: pbuf[row] = h[row] @ W2  (pure GEMM, plain stores) ----------------
__global__ __launch_bounds__(256, 4) void gemm2_kernel(
    const unsigned short* __restrict__ h,
    const unsigned short* __restrict__ wt2,
    const int* __restrict__ counts, const int* __restrict__ offsets,
    float* __restrict__ pbuf) {
    int rt = blockIdx.x;
    int e = -1, base = 0, rowbase = 0, cnt = 0;
    for (int ee = 0; ee < N_EXP; ++ee) {
        int c = counts[ee];
        int nt = (c + 127) >> 7;
        if (rt < base + nt) { e = ee; rowbase = (rt - base) << 7; cnt = c; break; }
        base += nt;
    }
    if (e < 0) return;
    int off = offsets[e];
    int colbase = blockIdx.y * 128;

    __shared__ __align__(16) char lds[2][16384];

    int t = threadIdx.x, lane = t & 63, wave = t >> 6;
    int wr = wave >> 1, wc = wave & 1;
    int q = lane >> 4, p = lane & 15;

    const unsigned short* wt2e = wt2 + (size_t)e * D_HID * D_EMBED;
    int r0 = rowbase + lane;      if (r0 >= cnt) r0 = cnt - 1;
    int r1 = rowbase + 64 + lane; if (r1 >= cnt) r1 = cnt - 1;
    const unsigned short* pA0 = h + (size_t)(off + r0) * D_HID;
    const unsigned short* pA1 = h + (size_t)(off + r1) * D_HID;
    const unsigned short* pB0 = wt2e + (size_t)(colbase + lane) * 8;
    const unsigned short* pB1 = wt2e + (size_t)(colbase + 64 + lane) * 8;

    f32x4 acc[4][4] = {};
    int aOff = (q * 128 + wr * 64 + p) * 16;
    int bOff = 8192 + (q * 128 + wc * 64 + p) * 16;

    auto STAGE = [&](int buf, int kt) {
        char* L = lds[buf];
        int ksl = wave;
        gload_lds16(pA0 + kt * 32 + ksl * 8, L + ksl * 2048);
        gload_lds16(pA1 + kt * 32 + ksl * 8, L + ksl * 2048 + 1024);
        gload_lds16(pB0 + (size_t)(kt * 4 + ksl) * (D_EMBED * 8), L + 8192 + ksl * 2048);
        gload_lds16(pB1 + (size_t)(kt * 4 + ksl) * (D_EMBED * 8), L + 8192 + ksl * 2048 + 1024);
    };
    auto COMPUTE = [&](int buf) {
        char* L = lds[buf];
        bf16x8 af[4];
#pragma unroll
        for (int m = 0; m < 4; ++m)
            af[m] = *reinterpret_cast<const bf16x8*>(L + aOff + m * 256);
#pragma unroll
        for (int n = 0; n < 4; ++n) {
            bf16x8 bn = *reinterpret_cast<const bf16x8*>(L + bOff + n * 256);
#pragma unroll
            for (int m = 0; m < 4; ++m)
                acc[m][n] = __builtin_amdgcn_mfma_f32_16x16x32_bf16(af[m], bn, acc[m][n], 0, 0, 0);
        }
    };

    STAGE(0, 0);
    __syncthreads();
    int cur = 0;
#pragma unroll 1
    for (int kt = 0; kt < 127; ++kt) {          // K=4096 / BK=32
        STAGE(cur ^ 1, kt + 1);
        COMPUTE(cur);
        __syncthreads();
        cur ^= 1;
    }
    COMPUTE(cur);

#pragma unroll
    for (int m = 0; m < 4; ++m)
#pragma unroll
        for (int reg = 0; reg < 4; ++reg) {
            int rl = wr * 64 + m * 16 + q * 4 + reg;
            int grow = rowbase + rl;
            if (grow >= cnt) continue;
            float* dst = pbuf + (size_t)(off + grow) * D_EMBED + colbase + wc * 64;
#pragma unroll
            for (int n = 0; n < 4; ++n) dst[n * 16 + p] = acc[m][n][reg];
        }
}

// ---------------- combine: out[tok] = pbuf[row0] + pbuf[row1] ----------------
__global__ __launch_bounds__(256) void combine_kernel(const float* __restrict__ pbuf,
                                                      const int* __restrict__ tok2row,
                                                      float* __restrict__ out) {
    int i = blockIdx.x * 256 + threadIdx.x;     // over N_TOK * 256 f32x4 units
    int tok = i >> 8, c = (i & 255) * 4;
    int r0 = tok2row[tok * 2], r1 = tok2row[tok * 2 + 1];
    f32x4 a = *reinterpret_cast<const f32x4*>(pbuf + (size_t)r0 * D_EMBED + c);
    f32x4 b = *reinterpret_cast<const f32x4*>(pbuf + (size_t)r1 * D_EMBED + c);
    *reinterpret_cast<f32x4*>(out + (size_t)tok * D_EMBED + c) = a + b;
}

extern "C" void kernel_launch(void* const* d_in, const int* in_sizes, int n_in,
                              void* d_out, int out_size, void* d_ws, size_t ws_size,
                              hipStream_t stream) {
    const float* x  = (const float*)d_in[0];
    const float* Wg = (const float*)d_in[1];
    const float* W1 = (const float*)d_in[2];
    const float* W3 = (const float*)d_in[3];
    const float* W2 = (const float*)d_in[4];
    float* out = (float*)d_out;

    char* ws = (char*)d_ws;
    size_t szW = (size_t)N_EXP * D_EMBED * D_HID;       // elems per weight tensor
    unsigned short* wt1 = (unsigned short*)ws;  ws += szW * 2;
    unsigned short* wt3 = (unsigned short*)ws;  ws += szW * 2;
    unsigned short* wt2 = (unsigned short*)ws;  ws += szW * 2;
    unsigned short* hbuf = (unsigned short*)ws; ws += (size_t)2 * N_TOK * D_HID * 2;
    unsigned short* xb = (unsigned short*)ws;   ws += (size_t)N_TOK * D_EMBED * 2;
    int*   toks    = (int*)ws;   ws += (size_t)N_EXP * CAP * 4;
    float* wgts    = (float*)ws; ws += (size_t)N_EXP * CAP * 4;
    int*   slots   = (int*)ws;   ws += (size_t)N_EXP * CAP * 4;
    int*   tok2row = (int*)ws;   ws += (size_t)N_TOK * 2 * 4;
    int*   counts  = (int*)ws;   ws += 8 * 4;
    int*   offsets = (int*)ws;   ws += 8 * 4;
    // pbuf (32 MB) aliases wt1 (64 MB): wt1 is dead after gemm1, pbuf written in gemm2
    float* pbuf = (float*)wt1;

    hipMemsetAsync(counts, 0, 8 * sizeof(int), stream);

    xcvt_kernel<<<(N_TOK * D_EMBED) / (256 * 8), 256, 0, stream>>>(x, xb, N_TOK * D_EMBED);
    pack_w<<<dim3(D_HID / 64, D_EMBED / 64, N_EXP), 256, 0, stream>>>(W1, wt1, D_EMBED, D_HID);
    pack_w<<<dim3(D_HID / 64, D_EMBED / 64, N_EXP), 256, 0, stream>>>(W3, wt3, D_EMBED, D_HID);
    pack_w<<<dim3(D_EMBED / 64, D_HID / 64, N_EXP), 256, 0, stream>>>(W2, wt2, D_HID, D_EMBED);
    gate_kernel<<<N_TOK / 4, 256, 0, stream>>>(x, Wg, counts, toks, wgts, slots);
    prefix_kernel<<<1, 64, 0, stream>>>(counts, offsets);
    build_map_kernel<<<(N_EXP * CAP) / 256, 256, 0, stream>>>(counts, offsets, toks, slots, tok2row);
    gemm1_kernel<<<dim3(72, 64), 256, 0, stream>>>(xb, wt1, wt3, counts, offsets, toks, wgts, hbuf);
    gemm2_kernel<<<dim3(72, 8), 256, 0, stream>>>(hbuf, wt2, counts, offsets, pbuf);
    combine_kernel<<<(N_TOK * 256) / 256, 256, 0, stream>>>(pbuf, tok2row, out);
}

// Round 3
// 638.061 us; speedup vs baseline: 1.0810x; 1.0810x over previous
//
#include <hip/hip_runtime.h>
#include <hip/hip_bf16.h>
#include <stdint.h>

#define D_EMBED 1024
#define D_HID   4096
#define N_TOK   4096
#define N_EXP   8
#define CAP     4096

typedef __attribute__((ext_vector_type(4))) float f32x4;
typedef __attribute__((ext_vector_type(8))) short bf16x8;

__device__ __forceinline__ unsigned short f2bf(float f) {
    unsigned int u = __builtin_bit_cast(unsigned int, f);
    u += 0x7fffu + ((u >> 16) & 1u);          // round-to-nearest-even
    return (unsigned short)(u >> 16);
}

__device__ __forceinline__ void gload_lds16(const void* g, void* l) {
    __builtin_amdgcn_global_load_lds(
        (const __attribute__((address_space(1))) unsigned int*)g,
        (__attribute__((address_space(3))) unsigned int*)l,
        16, 0, 0);
}

// ---------------- x f32 -> bf16 ----------------
__global__ __launch_bounds__(256) void xcvt_kernel(const float* __restrict__ x,
                                                   unsigned short* __restrict__ xb, int n) {
    int i = (blockIdx.x * 256 + threadIdx.x) * 8;
    if (i >= n) return;
    f32x4 a = *reinterpret_cast<const f32x4*>(x + i);
    f32x4 b = *reinterpret_cast<const f32x4*>(x + i + 4);
    bf16x8 o;
    o[0]=(short)f2bf(a[0]); o[1]=(short)f2bf(a[1]); o[2]=(short)f2bf(a[2]); o[3]=(short)f2bf(a[3]);
    o[4]=(short)f2bf(b[0]); o[5]=(short)f2bf(b[1]); o[6]=(short)f2bf(b[2]); o[7]=(short)f2bf(b[3]);
    *reinterpret_cast<bf16x8*>(xb + i) = o;
}

// ------- pack W [E][R][C] f32 -> tiled bf16 [E][R/8 kslice][C][8 j] -------
// element (e,ks,col,j) = W[e][ks*8 + j][col]
__global__ __launch_bounds__(256) void pack_w(const float* __restrict__ W,
                                              unsigned short* __restrict__ out, int R, int C) {
    int e = blockIdx.z, kb = blockIdx.y, cb = blockIdx.x;
    const float* Wp = W + (size_t)e * R * C + (size_t)(kb * 64) * C + cb * 64;
    unsigned short* op = out + (size_t)e * R * C;
    __shared__ unsigned short lds[64][72];
    int t = threadIdx.x;
    int r = t >> 2;
    int c0 = (t & 3) << 4;
    const float* src = Wp + (size_t)r * C + c0;
#pragma unroll
    for (int i = 0; i < 2; ++i) {
        f32x4 a = *reinterpret_cast<const f32x4*>(src + i * 8);
        f32x4 b = *reinterpret_cast<const f32x4*>(src + i * 8 + 4);
        bf16x8 o;
        o[0]=(short)f2bf(a[0]); o[1]=(short)f2bf(a[1]); o[2]=(short)f2bf(a[2]); o[3]=(short)f2bf(a[3]);
        o[4]=(short)f2bf(b[0]); o[5]=(short)f2bf(b[1]); o[6]=(short)f2bf(b[2]); o[7]=(short)f2bf(b[3]);
        *reinterpret_cast<bf16x8*>(&lds[r][c0 + i * 8]) = o;
    }
    __syncthreads();
#pragma unroll
    for (int i = 0; i < 2; ++i) {
        int cell = i * 256 + t;            // 0..511
        int ksl = cell >> 6, col = cell & 63;
        bf16x8 o;
#pragma unroll
        for (int j = 0; j < 8; ++j) o[j] = (short)lds[ksl * 8 + j][col];
        *reinterpret_cast<bf16x8*>(op + ((size_t)(kb * 8 + ksl) * C + cb * 64 + col) * 8) = o;
    }
}

// ---------------- gating ----------------
__global__ __launch_bounds__(256) void gate_kernel(const float* __restrict__ x,
                                                   const float* __restrict__ Wg,
                                                   int* __restrict__ counts,
                                                   int* __restrict__ toks,
                                                   float* __restrict__ wgts,
                                                   int* __restrict__ slots) {
    int wave = threadIdx.x >> 6;
    int lane = threadIdx.x & 63;
    int tok = blockIdx.x * 4 + wave;
    const float* xp = x + (size_t)tok * D_EMBED;
    float acc[8] = {0, 0, 0, 0, 0, 0, 0, 0};
#pragma unroll
    for (int i = 0; i < 16; ++i) {
        int d = lane + 64 * i;
        float xv = xp[d];
        f32x4 w0 = *reinterpret_cast<const f32x4*>(Wg + (size_t)d * 8);
        f32x4 w1 = *reinterpret_cast<const f32x4*>(Wg + (size_t)d * 8 + 4);
        acc[0] += xv * w0[0]; acc[1] += xv * w0[1]; acc[2] += xv * w0[2]; acc[3] += xv * w0[3];
        acc[4] += xv * w1[0]; acc[5] += xv * w1[1]; acc[6] += xv * w1[2]; acc[7] += xv * w1[3];
    }
#pragma unroll
    for (int e = 0; e < 8; ++e)
        for (int s = 32; s; s >>= 1) acc[e] += __shfl_xor(acc[e], s, 64);
    if (lane == 0) {
        int i0 = 0; float v0 = acc[0];
#pragma unroll
        for (int e = 1; e < 8; ++e) if (acc[e] > v0) { v0 = acc[e]; i0 = e; }
        int i1 = -1; float v1 = -1e30f;
#pragma unroll
        for (int e = 0; e < 8; ++e) if (e != i0 && acc[e] > v1) { v1 = acc[e]; i1 = e; }
        float ex = __expf(v1 - v0);
        float w0 = 1.0f / (1.0f + ex);
        float w1 = 1.0f - w0;
        int p0 = atomicAdd(&counts[i0], 1);
        toks[i0 * CAP + p0] = tok; wgts[i0 * CAP + p0] = w0; slots[i0 * CAP + p0] = 0;
        int p1 = atomicAdd(&counts[i1], 1);
        toks[i1 * CAP + p1] = tok; wgts[i1 * CAP + p1] = w1; slots[i1 * CAP + p1] = 1;
    }
}

__global__ void prefix_kernel(const int* __restrict__ counts, int* __restrict__ offsets) {
    if (threadIdx.x == 0) {
        int s = 0;
        for (int e = 0; e < N_EXP; ++e) { offsets[e] = s; s += counts[e]; }
    }
}

__global__ __launch_bounds__(256) void build_map_kernel(const int* __restrict__ counts,
                                                        const int* __restrict__ offsets,
                                                        const int* __restrict__ toks,
                                                        const int* __restrict__ slots,
                                                        int* __restrict__ tok2row) {
    int i = blockIdx.x * 256 + threadIdx.x;     // e*CAP + pos
    int e = i >> 12, pos = i & (CAP - 1);
    if (pos < counts[e])
        tok2row[toks[i] * 2 + slots[i]] = offsets[e] + pos;
}

// ------- GEMM1: h = w * silu(X@W1) * (X@W3); BM=128, BN=128(+128), BK=32 dbuf -------
// grid (x = colx 32, y = flat rowtile 72): id%8 = colx%8 -> B panel pinned per XCD
__global__ __launch_bounds__(256, 2) void gemm1_kernel(
    const unsigned short* __restrict__ xb,
    const unsigned short* __restrict__ wt1,
    const unsigned short* __restrict__ wt3,
    const int* __restrict__ counts, const int* __restrict__ offsets,
    const int* __restrict__ toks, const float* __restrict__ wgts,
    unsigned short* __restrict__ h) {
    int rt = blockIdx.y;                        // flat rowtile, expert-major
    int e = -1, base = 0, rowbase = 0, cnt = 0;
    for (int ee = 0; ee < N_EXP; ++ee) {
        int c = counts[ee];
        int nt = (c + 127) >> 7;
        if (rt < base + nt) { e = ee; rowbase = (rt - base) << 7; cnt = c; break; }
        base += nt;
    }
    if (e < 0) return;
    int off = offsets[e];
    int colbase = blockIdx.x * 128;

    __shared__ __align__(16) char lds[2][24576];    // A 8K | B1 8K | B3 8K

    int t = threadIdx.x, lane = t & 63, wave = t >> 6;
    int wr = wave >> 1, wc = wave & 1;
    int q = lane >> 4, p = lane & 15;

    const unsigned short* wt1e = wt1 + (size_t)e * D_EMBED * D_HID;
    const unsigned short* wt3e = wt3 + (size_t)e * D_EMBED * D_HID;

    int r0 = rowbase + lane;      if (r0 >= cnt) r0 = cnt - 1;
    int r1 = rowbase + 64 + lane; if (r1 >= cnt) r1 = cnt - 1;
    const unsigned short* pA0 = xb + (size_t)toks[e * CAP + r0] * D_EMBED;
    const unsigned short* pA1 = xb + (size_t)toks[e * CAP + r1] * D_EMBED;

    f32x4 acc1[4][4] = {};
    f32x4 acc3[4][4] = {};
    int aOff = (q * 2 + wr) * 1024 + p * 16;
    int bOff = (q * 2 + wc) * 1024 + p * 16;

    // LDS chunk c = ksl*2 + half (1KB each). A at 0, B1 at 8K, B3 at 16K.
    auto STAGE = [&](int buf, int kt) {
        char* L = lds[buf];
#pragma unroll
        for (int i = 0; i < 2; ++i) {
            int c = wave * 2 + i;               // ksl = wave, half = i
            int ksl = c >> 1, half = c & 1;
            gload_lds16((half ? pA1 : pA0) + kt * 32 + ksl * 8, L + c * 1024);
            size_t wofs = ((size_t)(kt * 4 + ksl) * D_HID + colbase + half * 64 + lane) * 8;
            gload_lds16(wt1e + wofs, L + 8192 + c * 1024);
            gload_lds16(wt3e + wofs, L + 16384 + c * 1024);
        }
    };
    auto COMPUTE = [&](int buf) {
        char* L = lds[buf];
        bf16x8 af[4];
#pragma unroll
        for (int m = 0; m < 4; ++m)
            af[m] = *reinterpret_cast<const bf16x8*>(L + aOff + m * 256);
#pragma unroll
        for (int n = 0; n < 4; ++n) {
            bf16x8 b1 = *reinterpret_cast<const bf16x8*>(L + 8192 + bOff + n * 256);
            bf16x8 b3 = *reinterpret_cast<const bf16x8*>(L + 16384 + bOff + n * 256);
#pragma unroll
            for (int m = 0; m < 4; ++m) {
                acc1[m][n] = __builtin_amdgcn_mfma_f32_16x16x32_bf16(af[m], b1, acc1[m][n], 0, 0, 0);
                acc3[m][n] = __builtin_amdgcn_mfma_f32_16x16x32_bf16(af[m], b3, acc3[m][n], 0, 0, 0);
            }
        }
    };

    STAGE(0, 0);
    __syncthreads();
    int cur = 0;
#pragma unroll 1
    for (int kt = 0; kt < 31; ++kt) {           // K=1024 / BK=32
        STAGE(cur ^ 1, kt + 1);                 // prefetch hides under MFMA
        COMPUTE(cur);
        __syncthreads();                        // one vmcnt(0)+barrier per tile
        cur ^= 1;
    }
    COMPUTE(cur);

#pragma unroll
    for (int m = 0; m < 4; ++m) {
#pragma unroll
        for (int reg = 0; reg < 4; ++reg) {
            int rl = wr * 64 + m * 16 + q * 4 + reg;
            int grow = rowbase + rl;
            if (grow >= cnt) continue;
            float w = wgts[e * CAP + grow];
            size_t hbase = (size_t)(off + grow) * D_HID + colbase + wc * 64;
#pragma unroll
            for (int n = 0; n < 4; ++n) {
                float a1 = acc1[m][n][reg], a3 = acc3[m][n][reg];
                float hv = (a1 / (1.0f + __expf(-a1))) * a3 * w;
                h[hbase + n * 16 + p] = f2bf(hv);
            }
        }
    }
}

// ------- GEMM2: pbuf[row] = h[row] @ W2; BM=256, BN=128, BK=32 dbuf, 512 thr -------
// grid (x = rowtile 48, y = colp 8): id%8 = rowtile%8 -> A rows pinned per XCD
__global__ __launch_bounds__(512, 4) void gemm2_kernel(
    const unsigned short* __restrict__ h,
    const unsigned short* __restrict__ wt2,
    const int* __restrict__ counts, const int* __restrict__ offsets,
    float* __restrict__ pbuf) {
    int rt = blockIdx.x;
    int e = -1, base = 0, rowbase = 0, cnt = 0;
    for (int ee = 0; ee < N_EXP; ++ee) {
        int c = counts[ee];
        int nt = (c + 255) >> 8;
        if (rt < base + nt) { e = ee; rowbase = (rt - base) << 8; cnt = c; break; }
        base += nt;
    }
    if (e < 0) return;
    int off = offsets[e];
    int colbase = blockIdx.y * 128;

    __shared__ __align__(16) char lds[2][24576];    // A 16K | B 8K

    int t = threadIdx.x, lane = t & 63, wave = t >> 6;   // 8 waves
    int wr = wave >> 1, wc = wave & 1;                   // wr 0..3, wc 0..1
    int q = lane >> 4, p = lane & 15;

    const unsigned short* wt2e = wt2 + (size_t)e * D_HID * D_EMBED;
    int rr0 = rowbase + lane;        if (rr0 >= cnt) rr0 = cnt - 1;
    int rr1 = rowbase + 64 + lane;   if (rr1 >= cnt) rr1 = cnt - 1;
    int rr2 = rowbase + 128 + lane;  if (rr2 >= cnt) rr2 = cnt - 1;
    int rr3 = rowbase + 192 + lane;  if (rr3 >= cnt) rr3 = cnt - 1;
    const unsigned short* pA0 = h + (size_t)(off + rr0) * D_HID;
    const unsigned short* pA1 = h + (size_t)(off + rr1) * D_HID;
    const unsigned short* pA2 = h + (size_t)(off + rr2) * D_HID;
    const unsigned short* pA3 = h + (size_t)(off + rr3) * D_HID;

    f32x4 acc[4][4] = {};
    int aOff = (q * 4 + wr) * 1024 + p * 16;            // A chunk = ksl*4 + quarter
    int bOff = 16384 + (q * 2 + wc) * 1024 + p * 16;    // B chunk = ksl*2 + half

    auto STAGE = [&](int buf, int kt) {
        char* L = lds[buf];
#pragma unroll
        for (int i = 0; i < 2; ++i) {
            int c = wave * 2 + i;               // 0..15: ksl = c>>2, quarter = c&3
            int ksl = c >> 2, qt = c & 3;
            const unsigned short* pAq = (qt == 0) ? pA0 : (qt == 1) ? pA1 : (qt == 2) ? pA2 : pA3;
            gload_lds16(pAq + kt * 32 + ksl * 8, L + c * 1024);
        }
        int ksl = wave >> 1, half = wave & 1;   // B chunk = wave
        gload_lds16(wt2e + ((size_t)(kt * 4 + ksl) * D_EMBED + colbase + half * 64 + lane) * 8,
                    L + 16384 + wave * 1024);
    };
    auto COMPUTE = [&](int buf) {
        char* L = lds[buf];
        bf16x8 af[4];
#pragma unroll
        for (int m = 0; m < 4; ++m)
            af[m] = *reinterpret_cast<const bf16x8*>(L + aOff + m * 256);
#pragma unroll
        for (int n = 0; n < 4; ++n) {
            bf16x8 bn = *reinterpret_cast<const bf16x8*>(L + bOff + n * 256);
#pragma unroll
            for (int m = 0; m < 4; ++m)
                acc[m][n] = __builtin_amdgcn_mfma_f32_16x16x32_bf16(af[m], bn, acc[m][n], 0, 0, 0);
        }
    };

    STAGE(0, 0);
    __syncthreads();
    int cur = 0;
#pragma unroll 1
    for (int kt = 0; kt < 127; ++kt) {          // K=4096 / BK=32
        STAGE(cur ^ 1, kt + 1);
        COMPUTE(cur);
        __syncthreads();
        cur ^= 1;
    }
    COMPUTE(cur);

#pragma unroll
    for (int m = 0; m < 4; ++m)
#pragma unroll
        for (int reg = 0; reg < 4; ++reg) {
            int rl = wr * 64 + m * 16 + q * 4 + reg;
            int grow = rowbase + rl;
            if (grow >= cnt) continue;
            float* dst = pbuf + (size_t)(off + grow) * D_EMBED + colbase + wc * 64;
#pragma unroll
            for (int n = 0; n < 4; ++n) dst[n * 16 + p] = acc[m][n][reg];
        }
}

// ---------------- combine: out[tok] = pbuf[row0] + pbuf[row1] ----------------
__global__ __launch_bounds__(256) void combine_kernel(const float* __restrict__ pbuf,
                                                      const int* __restrict__ tok2row,
                                                      float* __restrict__ out) {
    int i = blockIdx.x * 256 + threadIdx.x;     // over N_TOK * 256 f32x4 units
    int tok = i >> 8, c = (i & 255) * 4;
    int r0 = tok2row[tok * 2], r1 = tok2row[tok * 2 + 1];
    f32x4 a = *reinterpret_cast<const f32x4*>(pbuf + (size_t)r0 * D_EMBED + c);
    f32x4 b = *reinterpret_cast<const f32x4*>(pbuf + (size_t)r1 * D_EMBED + c);
    *reinterpret_cast<f32x4*>(out + (size_t)tok * D_EMBED + c) = a + b;
}

extern "C" void kernel_launch(void* const* d_in, const int* in_sizes, int n_in,
                              void* d_out, int out_size, void* d_ws, size_t ws_size,
                              hipStream_t stream) {
    const float* x  = (const float*)d_in[0];
    const float* Wg = (const float*)d_in[1];
    const float* W1 = (const float*)d_in[2];
    const float* W3 = (const float*)d_in[3];
    const float* W2 = (const float*)d_in[4];
    float* out = (float*)d_out;

    char* ws = (char*)d_ws;
    size_t szW = (size_t)N_EXP * D_EMBED * D_HID;       // elems per weight tensor
    unsigned short* wt1 = (unsigned short*)ws;  ws += szW * 2;
    unsigned short* wt3 = (unsigned short*)ws;  ws += szW * 2;
    unsigned short* wt2 = (unsigned short*)ws;  ws += szW * 2;
    unsigned short* hbuf = (unsigned short*)ws; ws += (size_t)2 * N_TOK * D_HID * 2;
    unsigned short* xb = (unsigned short*)ws;   ws += (size_t)N_TOK * D_EMBED * 2;
    int*   toks    = (int*)ws;   ws += (size_t)N_EXP * CAP * 4;
    float* wgts    = (float*)ws; ws += (size_t)N_EXP * CAP * 4;
    int*   slots   = (int*)ws;   ws += (size_t)N_EXP * CAP * 4;
    int*   tok2row = (int*)ws;   ws += (size_t)N_TOK * 2 * 4;
    int*   counts  = (int*)ws;   ws += 8 * 4;
    int*   offsets = (int*)ws;   ws += 8 * 4;
    // pbuf (32 MB) aliases wt1 (64 MB): wt1 dead after gemm1, pbuf written in gemm2
    float* pbuf = (float*)wt1;

    hipMemsetAsync(counts, 0, 8 * sizeof(int), stream);

    xcvt_kernel<<<(N_TOK * D_EMBED) / (256 * 8), 256, 0, stream>>>(x, xb, N_TOK * D_EMBED);
    pack_w<<<dim3(D_HID / 64, D_EMBED / 64, N_EXP), 256, 0, stream>>>(W1, wt1, D_EMBED, D_HID);
    pack_w<<<dim3(D_HID / 64, D_EMBED / 64, N_EXP), 256, 0, stream>>>(W3, wt3, D_EMBED, D_HID);
    pack_w<<<dim3(D_EMBED / 64, D_HID / 64, N_EXP), 256, 0, stream>>>(W2, wt2, D_HID, D_EMBED);
    gate_kernel<<<N_TOK / 4, 256, 0, stream>>>(x, Wg, counts, toks, wgts, slots);
    prefix_kernel<<<1, 64, 0, stream>>>(counts, offsets);
    build_map_kernel<<<(N_EXP * CAP) / 256, 256, 0, stream>>>(counts, offsets, toks, slots, tok2row);
    gemm1_kernel<<<dim3(32, 72), 256, 0, stream>>>(xb, wt1, wt3, counts, offsets, toks, wgts, hbuf);
    gemm2_kernel<<<dim3(48, 8), 512, 0, stream>>>(hbuf, wt2, counts, offsets, pbuf);
    combine_kernel<<<(N_TOK * 256) / 256, 256, 0, stream>>>(pbuf, tok2row, out);
}

// Round 4
// 557.555 us; speedup vs baseline: 1.2371x; 1.1444x over previous
//
#include <hip/hip_runtime.h>
#include <hip/hip_bf16.h>
#include <stdint.h>

#define D_EMBED 1024
#define D_HID   4096
#define N_TOK   4096
#define N_EXP   8
#define CAP     4096
#define NROWA   8320            // 8192 rows + 128 slack for tile overshoot

typedef __attribute__((ext_vector_type(4))) float f32x4;
typedef __attribute__((ext_vector_type(8))) short bf16x8;

__device__ __forceinline__ unsigned short f2bf(float f) {
    unsigned int u = __builtin_bit_cast(unsigned int, f);
    u += 0x7fffu + ((u >> 16) & 1u);          // round-to-nearest-even
    return (unsigned short)(u >> 16);
}

__device__ __forceinline__ void gload_lds16(const void* g, void* l) {
    __builtin_amdgcn_global_load_lds(
        (const __attribute__((address_space(1))) unsigned int*)g,
        (__attribute__((address_space(3))) unsigned int*)l,
        16, 0, 0);
}

// ------- pack W [E][R][C] f32 -> tiled bf16 [E][R/8 kslice][C][8 j] -------
__global__ __launch_bounds__(256) void pack_w(const float* __restrict__ W,
                                              unsigned short* __restrict__ out, int R, int C) {
    int e = blockIdx.z, kb = blockIdx.y, cb = blockIdx.x;
    const float* Wp = W + (size_t)e * R * C + (size_t)(kb * 64) * C + cb * 64;
    unsigned short* op = out + (size_t)e * R * C;
    __shared__ unsigned short lds[64][72];
    int t = threadIdx.x;
    int r = t >> 2;
    int c0 = (t & 3) << 4;
    const float* src = Wp + (size_t)r * C + c0;
#pragma unroll
    for (int i = 0; i < 2; ++i) {
        f32x4 a = *reinterpret_cast<const f32x4*>(src + i * 8);
        f32x4 b = *reinterpret_cast<const f32x4*>(src + i * 8 + 4);
        bf16x8 o;
        o[0]=(short)f2bf(a[0]); o[1]=(short)f2bf(a[1]); o[2]=(short)f2bf(a[2]); o[3]=(short)f2bf(a[3]);
        o[4]=(short)f2bf(b[0]); o[5]=(short)f2bf(b[1]); o[6]=(short)f2bf(b[2]); o[7]=(short)f2bf(b[3]);
        *reinterpret_cast<bf16x8*>(&lds[r][c0 + i * 8]) = o;
    }
    __syncthreads();
#pragma unroll
    for (int i = 0; i < 2; ++i) {
        int cell = i * 256 + t;            // 0..511
        int ksl = cell >> 6, col = cell & 63;
        bf16x8 o;
#pragma unroll
        for (int j = 0; j < 8; ++j) o[j] = (short)lds[ksl * 8 + j][col];
        *reinterpret_cast<bf16x8*>(op + ((size_t)(kb * 8 + ksl) * C + cb * 64 + col) * 8) = o;
    }
}

// ---------------- gating ----------------
__global__ __launch_bounds__(256) void gate_kernel(const float* __restrict__ x,
                                                   const float* __restrict__ Wg,
                                                   int* __restrict__ counts,
                                                   int* __restrict__ toks,
                                                   float* __restrict__ wgts,
                                                   int* __restrict__ slots) {
    int wave = threadIdx.x >> 6;
    int lane = threadIdx.x & 63;
    int tok = blockIdx.x * 4 + wave;
    const float* xp = x + (size_t)tok * D_EMBED;
    float acc[8] = {0, 0, 0, 0, 0, 0, 0, 0};
#pragma unroll
    for (int i = 0; i < 16; ++i) {
        int d = lane + 64 * i;
        float xv = xp[d];
        f32x4 w0 = *reinterpret_cast<const f32x4*>(Wg + (size_t)d * 8);
        f32x4 w1 = *reinterpret_cast<const f32x4*>(Wg + (size_t)d * 8 + 4);
        acc[0] += xv * w0[0]; acc[1] += xv * w0[1]; acc[2] += xv * w0[2]; acc[3] += xv * w0[3];
        acc[4] += xv * w1[0]; acc[5] += xv * w1[1]; acc[6] += xv * w1[2]; acc[7] += xv * w1[3];
    }
#pragma unroll
    for (int e = 0; e < 8; ++e)
        for (int s = 32; s; s >>= 1) acc[e] += __shfl_xor(acc[e], s, 64);
    if (lane == 0) {
        int i0 = 0; float v0 = acc[0];
#pragma unroll
        for (int e = 1; e < 8; ++e) if (acc[e] > v0) { v0 = acc[e]; i0 = e; }
        int i1 = -1; float v1 = -1e30f;
#pragma unroll
        for (int e = 0; e < 8; ++e) if (e != i0 && acc[e] > v1) { v1 = acc[e]; i1 = e; }
        float ex = __expf(v1 - v0);
        float w0 = 1.0f / (1.0f + ex);
        float w1 = 1.0f - w0;
        int p0 = atomicAdd(&counts[i0], 1);
        toks[i0 * CAP + p0] = tok; wgts[i0 * CAP + p0] = w0; slots[i0 * CAP + p0] = 0;
        int p1 = atomicAdd(&counts[i1], 1);
        toks[i1 * CAP + p1] = tok; wgts[i1 * CAP + p1] = w1; slots[i1 * CAP + p1] = 1;
    }
}

__global__ void prefix_kernel(const int* __restrict__ counts, int* __restrict__ offsets) {
    if (threadIdx.x == 0) {
        int s = 0;
        for (int e = 0; e < N_EXP; ++e) { offsets[e] = s; s += counts[e]; }
    }
}

__global__ __launch_bounds__(256) void build_map_kernel(const int* __restrict__ counts,
                                                        const int* __restrict__ offsets,
                                                        const int* __restrict__ toks,
                                                        const int* __restrict__ slots,
                                                        int* __restrict__ tok2row) {
    int i = blockIdx.x * 256 + threadIdx.x;     // e*CAP + pos
    int e = i >> 12, pos = i & (CAP - 1);
    if (pos < counts[e])
        tok2row[toks[i] * 2 + slots[i]] = offsets[e] + pos;
}

// ------- gather x rows (by routing) into compacted k-packed A: xg[s][row][8] -------
// xg element (s, grow, j) = bf16(x[tok(grow)][s*8+j]); rows >= cnt untouched.
__global__ __launch_bounds__(256) void gather_x_kernel(
    const float* __restrict__ x,
    const int* __restrict__ counts, const int* __restrict__ offsets,
    const int* __restrict__ toks,
    unsigned short* __restrict__ xg) {
    int rt = blockIdx.x;                        // flat 64-row chunk, expert-major
    int e = -1, base = 0, rowbase = 0, cnt = 0;
    for (int ee = 0; ee < N_EXP; ++ee) {
        int c = counts[ee];
        int nt = (c + 63) >> 6;
        if (rt < base + nt) { e = ee; rowbase = (rt - base) << 6; cnt = c; break; }
        base += nt;
    }
    if (e < 0) return;
    int off = offsets[e];
    int kb = blockIdx.y;                        // 64-k tile
    __shared__ unsigned short lds[64][72];
    int t = threadIdx.x;
    int r = t >> 2, ck = t & 3;
    int pos = rowbase + r;
    unsigned short tmp[16];
    if (pos < cnt) {
        int tok = toks[e * CAP + pos];
        const float* src = x + (size_t)tok * D_EMBED + kb * 64 + ck * 16;
#pragma unroll
        for (int i = 0; i < 4; ++i) {
            f32x4 v = *reinterpret_cast<const f32x4*>(src + i * 4);
#pragma unroll
            for (int j = 0; j < 4; ++j) tmp[i * 4 + j] = f2bf(v[j]);
        }
    } else {
#pragma unroll
        for (int i = 0; i < 16; ++i) tmp[i] = 0;
    }
#pragma unroll
    for (int i = 0; i < 16; ++i) lds[r][ck * 16 + i] = tmp[i];
    __syncthreads();
    int sl = t >> 5, rr = (t & 31) * 2;
#pragma unroll
    for (int w = 0; w < 2; ++w) {
        int rw = rr + w;
        if (rowbase + rw >= cnt) continue;      // never stomp next expert's rows
        bf16x8 o;
#pragma unroll
        for (int j = 0; j < 8; ++j) o[j] = (short)lds[rw][sl * 8 + j];
        *reinterpret_cast<bf16x8*>(xg + ((size_t)(kb * 8 + sl) * NROWA + off + rowbase + rw) * 8) = o;
    }
}

// ------- GEMM1: hp = w * silu(X@W1) * (X@W3); 128x(128|128), BK=64, single buf -------
// grid (x = colx 32, y = flat rowtile 72): XCD = x%8 -> B panels pinned per XCD
__global__ __launch_bounds__(256, 2) void gemm1_kernel(
    const unsigned short* __restrict__ xg,
    const unsigned short* __restrict__ wt1,
    const unsigned short* __restrict__ wt3,
    const int* __restrict__ counts, const int* __restrict__ offsets,
    const float* __restrict__ wgts,
    unsigned short* __restrict__ hp) {
    int rt = blockIdx.y;
    int e = -1, base = 0, rowbase = 0, cnt = 0;
    for (int ee = 0; ee < N_EXP; ++ee) {
        int c = counts[ee];
        int nt = (c + 127) >> 7;
        if (rt < base + nt) { e = ee; rowbase = (rt - base) << 7; cnt = c; break; }
        base += nt;
    }
    if (e < 0) return;
    int off = offsets[e];
    int colbase = blockIdx.x * 128;

    __shared__ __align__(16) char lds[49152];   // A 16K | B1 16K | B3 16K

    int t = threadIdx.x, lane = t & 63, wave = t >> 6;
    int wr = wave >> 1, wc = wave & 1;
    int q = lane >> 4, p = lane & 15;

    const unsigned short* wt1e = wt1 + (size_t)e * D_EMBED * D_HID;
    const unsigned short* wt3e = wt3 + (size_t)e * D_EMBED * D_HID;
    const unsigned short* pA = xg + (size_t)(off + rowbase) * 8;   // row base (packed)

    f32x4 acc1[4][4] = {};
    f32x4 acc3[4][4] = {};

#pragma unroll 1
    for (int kt = 0; kt < 16; ++kt) {           // K=1024 / BK=64
        // stage: 16 A chunks + 16 B1 + 16 B3, 1KB each, all linear-coalesced
#pragma unroll
        for (int i = 0; i < 4; ++i) {
            int c = wave * 4 + i;               // 0..15: ksl = c>>1, half = c&1
            int ksl = c >> 1, half = c & 1;
            size_t s = (size_t)(kt * 8 + ksl);
            gload_lds16(pA + (s * NROWA + half * 64 + lane) * 8, lds + c * 1024);
            size_t wofs = (s * D_HID + colbase + half * 64 + lane) * 8;
            gload_lds16(wt1e + wofs, lds + 16384 + c * 1024);
            gload_lds16(wt3e + wofs, lds + 32768 + c * 1024);
        }
        __syncthreads();                        // drains vmcnt(0)
#pragma unroll
        for (int ks = 0; ks < 2; ++ks) {
            int aC = ((ks * 4 + q) * 2 + wr) * 1024 + p * 16;
            int bC = ((ks * 4 + q) * 2 + wc) * 1024 + p * 16;
            bf16x8 af[4];
#pragma unroll
            for (int m = 0; m < 4; ++m)
                af[m] = *reinterpret_cast<const bf16x8*>(lds + aC + m * 256);
#pragma unroll
            for (int n = 0; n < 4; ++n) {
                bf16x8 b1 = *reinterpret_cast<const bf16x8*>(lds + 16384 + bC + n * 256);
                bf16x8 b3 = *reinterpret_cast<const bf16x8*>(lds + 32768 + bC + n * 256);
#pragma unroll
                for (int m = 0; m < 4; ++m) {
                    acc1[m][n] = __builtin_amdgcn_mfma_f32_16x16x32_bf16(af[m], b1, acc1[m][n], 0, 0, 0);
                    acc3[m][n] = __builtin_amdgcn_mfma_f32_16x16x32_bf16(af[m], b3, acc3[m][n], 0, 0, 0);
                }
            }
        }
        __syncthreads();
    }

#pragma unroll
    for (int m = 0; m < 4; ++m) {
#pragma unroll
        for (int reg = 0; reg < 4; ++reg) {
            int rl = wr * 64 + m * 16 + q * 4 + reg;
            int grow = rowbase + rl;
            if (grow >= cnt) continue;
            float w = wgts[e * CAP + grow];
            size_t row = (size_t)(off + grow);
#pragma unroll
            for (int n = 0; n < 4; ++n) {
                float a1 = acc1[m][n][reg], a3 = acc3[m][n][reg];
                float hv = (a1 / (1.0f + __expf(-a1))) * a3 * w;
                int colg = colbase + wc * 64 + n * 16 + p;
                hp[((size_t)(colg >> 3) * NROWA + row) * 8 + (colg & 7)] = f2bf(hv);
            }
        }
    }
}

// ------- GEMM2: pbuf[row] = hp[row] @ W2; 128x128, BK=64, single buf -------
// grid (x = rowtile 72, y = colp 8): XCD = x%8 -> A rows pinned per XCD
__global__ __launch_bounds__(256, 2) void gemm2_kernel(
    const unsigned short* __restrict__ hp,
    const unsigned short* __restrict__ wt2,
    const int* __restrict__ counts, const int* __restrict__ offsets,
    float* __restrict__ pbuf) {
    int rt = blockIdx.x;
    int e = -1, base = 0, rowbase = 0, cnt = 0;
    for (int ee = 0; ee < N_EXP; ++ee) {
        int c = counts[ee];
        int nt = (c + 127) >> 7;
        if (rt < base + nt) { e = ee; rowbase = (rt - base) << 7; cnt = c; break; }
        base += nt;
    }
    if (e < 0) return;
    int off = offsets[e];
    int colbase = blockIdx.y * 128;

    __shared__ __align__(16) char lds[32768];   // A 16K | B 16K

    int t = threadIdx.x, lane = t & 63, wave = t >> 6;
    int wr = wave >> 1, wc = wave & 1;
    int q = lane >> 4, p = lane & 15;

    const unsigned short* wt2e = wt2 + (size_t)e * D_HID * D_EMBED;
    const unsigned short* pA = hp + (size_t)(off + rowbase) * 8;

    f32x4 acc[4][4] = {};

#pragma unroll 1
    for (int kt = 0; kt < 64; ++kt) {           // K=4096 / BK=64
#pragma unroll
        for (int i = 0; i < 4; ++i) {
            int c = wave * 4 + i;
            int ksl = c >> 1, half = c & 1;
            size_t s = (size_t)(kt * 8 + ksl);
            gload_lds16(pA + (s * NROWA + half * 64 + lane) * 8, lds + c * 1024);
            gload_lds16(wt2e + (s * D_EMBED + colbase + half * 64 + lane) * 8,
                        lds + 16384 + c * 1024);
        }
        __syncthreads();
#pragma unroll
        for (int ks = 0; ks < 2; ++ks) {
            int aC = ((ks * 4 + q) * 2 + wr) * 1024 + p * 16;
            int bC = 16384 + ((ks * 4 + q) * 2 + wc) * 1024 + p * 16;
            bf16x8 af[4];
#pragma unroll
            for (int m = 0; m < 4; ++m)
                af[m] = *reinterpret_cast<const bf16x8*>(lds + aC + m * 256);
#pragma unroll
            for (int n = 0; n < 4; ++n) {
                bf16x8 bn = *reinterpret_cast<const bf16x8*>(lds + bC + n * 256);
#pragma unroll
                for (int m = 0; m < 4; ++m)
                    acc[m][n] = __builtin_amdgcn_mfma_f32_16x16x32_bf16(af[m], bn, acc[m][n], 0, 0, 0);
            }
        }
        __syncthreads();
    }

#pragma unroll
    for (int m = 0; m < 4; ++m)
#pragma unroll
        for (int reg = 0; reg < 4; ++reg) {
            int rl = wr * 64 + m * 16 + q * 4 + reg;
            int grow = rowbase + rl;
            if (grow >= cnt) continue;
            float* dst = pbuf + (size_t)(off + grow) * D_EMBED + colbase + wc * 64;
#pragma unroll
            for (int n = 0; n < 4; ++n) dst[n * 16 + p] = acc[m][n][reg];
        }
}

// ---------------- combine: out[tok] = pbuf[row0] + pbuf[row1] ----------------
__global__ __launch_bounds__(256) void combine_kernel(const float* __restrict__ pbuf,
                                                      const int* __restrict__ tok2row,
                                                      float* __restrict__ out) {
    int i = blockIdx.x * 256 + threadIdx.x;     // over N_TOK * 256 f32x4 units
    int tok = i >> 8, c = (i & 255) * 4;
    int r0 = tok2row[tok * 2], r1 = tok2row[tok * 2 + 1];
    f32x4 a = *reinterpret_cast<const f32x4*>(pbuf + (size_t)r0 * D_EMBED + c);
    f32x4 b = *reinterpret_cast<const f32x4*>(pbuf + (size_t)r1 * D_EMBED + c);
    *reinterpret_cast<f32x4*>(out + (size_t)tok * D_EMBED + c) = a + b;
}

extern "C" void kernel_launch(void* const* d_in, const int* in_sizes, int n_in,
                              void* d_out, int out_size, void* d_ws, size_t ws_size,
                              hipStream_t stream) {
    const float* x  = (const float*)d_in[0];
    const float* Wg = (const float*)d_in[1];
    const float* W1 = (const float*)d_in[2];
    const float* W3 = (const float*)d_in[3];
    const float* W2 = (const float*)d_in[4];
    float* out = (float*)d_out;

    char* ws = (char*)d_ws;
    size_t szW = (size_t)N_EXP * D_EMBED * D_HID;       // elems per weight tensor
    unsigned short* wt1 = (unsigned short*)ws;  ws += szW * 2;
    unsigned short* wt3 = (unsigned short*)ws;  ws += szW * 2;
    unsigned short* wt2 = (unsigned short*)ws;  ws += szW * 2;
    unsigned short* hp  = (unsigned short*)ws;  ws += (size_t)(D_HID / 8) * NROWA * 8 * 2;
    unsigned short* xg  = (unsigned short*)ws;  ws += (size_t)(D_EMBED / 8) * NROWA * 8 * 2;
    int*   toks    = (int*)ws;   ws += (size_t)N_EXP * CAP * 4;
    float* wgts    = (float*)ws; ws += (size_t)N_EXP * CAP * 4;
    int*   slots   = (int*)ws;   ws += (size_t)N_EXP * CAP * 4;
    int*   tok2row = (int*)ws;   ws += (size_t)N_TOK * 2 * 4;
    int*   counts  = (int*)ws;   ws += 8 * 4;
    int*   offsets = (int*)ws;   ws += 8 * 4;
    // pbuf (33.5 MB) aliases wt1 (67 MB): wt1 dead after gemm1, pbuf written in gemm2
    float* pbuf = (float*)wt1;

    hipMemsetAsync(counts, 0, 8 * sizeof(int), stream);

    pack_w<<<dim3(D_HID / 64, D_EMBED / 64, N_EXP), 256, 0, stream>>>(W1, wt1, D_EMBED, D_HID);
    pack_w<<<dim3(D_HID / 64, D_EMBED / 64, N_EXP), 256, 0, stream>>>(W3, wt3, D_EMBED, D_HID);
    pack_w<<<dim3(D_EMBED / 64, D_HID / 64, N_EXP), 256, 0, stream>>>(W2, wt2, D_HID, D_EMBED);
    gate_kernel<<<N_TOK / 4, 256, 0, stream>>>(x, Wg, counts, toks, wgts, slots);
    prefix_kernel<<<1, 64, 0, stream>>>(counts, offsets);
    build_map_kernel<<<(N_EXP * CAP) / 256, 256, 0, stream>>>(counts, offsets, toks, slots, tok2row);
    gather_x_kernel<<<dim3(136, D_EMBED / 64), 256, 0, stream>>>(x, counts, offsets, toks, xg);
    gemm1_kernel<<<dim3(32, 72), 256, 0, stream>>>(xg, wt1, wt3, counts, offsets, wgts, hp);
    gemm2_kernel<<<dim3(72, 8), 256, 0, stream>>>(hp, wt2, counts, offsets, pbuf);
    combine_kernel<<<(N_TOK * 256) / 256, 256, 0, stream>>>(pbuf, tok2row, out);
}